// Round 2
// baseline (150.705 us; speedup 1.0000x reference)
//
#include <hip/hip_runtime.h>
#include <hip/hip_bf16.h>

#define N_NODES 50000
#define N_EDGES 800000
#define FEAT 64
#define RANGE 32        // nodes per K2 block
#define NBINS 1563      // ceil(50000/32)
#define K1B 250         // bin blocks; EPB = 3200 (multiple of 4)
#define EPB (N_EDGES / K1B)
#define SUB 16          // slots per (range, bin-block) chunk = one 64B line; fill ~ Poisson(2.05)
#define RSTRIDE 4096    // ent ints per range: 256 padded chunks x 16 (guard-free prefetch)
#define CAPP 48         // per-node bucket capacity (deg ~ Poisson(16); P(>48) ~ 1e-11)
#define BSTRIDE 52      // bucket row stride in ints (16B-aligned, odd bank step)
#define DUMMY N_NODES   // zero row index for degree padding
#define CONVB 391       // ceil((N_NODES+1)*FEAT/8 / 1024) conv blocks in fused K01

// ============================================================================
// ROUND 2 = DIAGNOSTIC ROUND (kernels byte-identical to round 1).
// Two rounds of structural changes moved dur_us by ~1% each -> suspect a fixed
// floor (ws re-poison fills / launch gaps) dominates; per-kernel split unknown
// because top-5 shows only 45us harness fills. This round doubles the kernel
// work to expose the split:
//   * conv_bin launched twice (idempotent)           -> Ddur += K01
//   * sort_gather_mm launched with 2x grid (WAW-safe)-> Ddur += K2, and the
//     single 2xK2 dispatch enters top-5 WITH counters if 2xK2 > 44us.
// Interpretation: dur_new - 115.7 = K01 + K2 (+~2us).
// ============================================================================

static __device__ __forceinline__ unsigned short f2bu(float f) {
    __hip_bfloat16 h = __float2bfloat16(f);
    return __builtin_bit_cast(unsigned short, h);
}

// K01: fused conv + bin (see round-1 notes: 16 waves/CU bin, conv overlaps bin).
__global__ __launch_bounds__(1024) void conv_bin_kernel(
    const float* __restrict__ src_feat,
    unsigned short* __restrict__ src16,
    const int* __restrict__ edge_src,
    const int* __restrict__ edge_dst,
    int* __restrict__ counts,       // [K1B][NBINS]  (b-major: sequential publish)
    int* __restrict__ ent)          // [NBINS][RSTRIDE] ; chunk (r,b) at r*4096+b*16
{
    __shared__ int h[NBINS];        // 6.25 KB cursors (bin blocks only)
    int tid = threadIdx.x;

    if (blockIdx.x < CONVB) {
        // ---- conv part: 8 floats -> 8 bf16 per thread ----
        int base = (blockIdx.x * 1024 + tid) * 8;
        if (base >= (N_NODES + 1) * FEAT) return;
        uint4 o;
        if (base < N_NODES * FEAT) {
            float4 a = *(const float4*)(src_feat + base);
            float4 b = *(const float4*)(src_feat + base + 4);
            o.x = (unsigned)f2bu(a.x) | ((unsigned)f2bu(a.y) << 16);
            o.y = (unsigned)f2bu(a.z) | ((unsigned)f2bu(a.w) << 16);
            o.z = (unsigned)f2bu(b.x) | ((unsigned)f2bu(b.y) << 16);
            o.w = (unsigned)f2bu(b.z) | ((unsigned)f2bu(b.w) << 16);
        } else {
            o = make_uint4(0, 0, 0, 0);
        }
        *(uint4*)(src16 + base) = o;
        return;
    }

    // ---- bin part: deterministic single-pass binning ----
    int b = blockIdx.x - CONVB;
    for (int r = tid; r < NBINS; r += 1024) h[r] = 0;
    __syncthreads();

    if (tid < EPB / 4) {            // exactly 800 threads, one int4 each
        int e = b * EPB + tid * 4;
        int4 s4 = *(const int4*)(edge_src + e);
        int4 d4 = *(const int4*)(edge_dst + e);
        int r0 = d4.x >> 5, r1 = d4.y >> 5, r2 = d4.z >> 5, r3 = d4.w >> 5;
        int p0 = atomicAdd(&h[r0], 1);
        int p1 = atomicAdd(&h[r1], 1);
        int p2 = atomicAdd(&h[r2], 1);
        int p3 = atomicAdd(&h[r3], 1);
        if (p0 < SUB) ent[r0 * RSTRIDE + b * SUB + p0] = ((d4.x & 31) << 16) | s4.x;
        if (p1 < SUB) ent[r1 * RSTRIDE + b * SUB + p1] = ((d4.y & 31) << 16) | s4.y;
        if (p2 < SUB) ent[r2 * RSTRIDE + b * SUB + p2] = ((d4.z & 31) << 16) | s4.z;
        if (p3 < SUB) ent[r3 * RSTRIDE + b * SUB + p3] = ((d4.w & 31) << 16) | s4.w;
    }
    __syncthreads();

    // Publish counts: contiguous 6.25 KB sequential write per block.
    for (int r = tid; r < NBINS; r += 1024) {
        int c = h[r];
        counts[b * NBINS + r] = (c > SUB) ? SUB : c;
    }
}

// Phase-B pipeline macros — all array indices compile-time (rule #20).
#define RDIDX(ID, Q)                                                          \
    _Pragma("unroll")                                                         \
    for (int m_ = 0; m_ < 4; ++m_) {                                          \
        int raw_ = bucket_w[(wave * 4 + m_) * BSTRIDE + (Q) * 4 + sub];       \
        ID[m_] = ((Q) < rows4[m_]) ? raw_ : DUMMY;                            \
    }
#define GLOAD(L, ID)                                                          \
    _Pragma("unroll")                                                         \
    for (int m_ = 0; m_ < 4; ++m_)                                            \
        L[m_] = *(const uint2*)(src16 + (size_t)ID[m_] * FEAT + fc * 4);
#define ACCUM(L)                                                              \
    _Pragma("unroll")                                                         \
    for (int m_ = 0; m_ < 4; ++m_) {                                          \
        acc[m_][0] += __uint_as_float(L[m_].x << 16);                         \
        acc[m_][1] += __uint_as_float(L[m_].x & 0xFFFF0000u);                 \
        acc[m_][2] += __uint_as_float(L[m_].y << 16);                         \
        acc[m_][3] += __uint_as_float(L[m_].y & 0xFFFF0000u);                 \
    }

// K2: identical to round 1, EXCEPT the grid is doubled for this diagnostic:
// blocks [0,NBINS) and [NBINS,2*NBINS) compute the same range r (benign WAW,
// identical-to-ulp values). One dispatch of ~2xK2 duration -> top-5 visible.
__global__ __launch_bounds__(512, 6) void sort_gather_mm_kernel(
    const unsigned short* __restrict__ src16,
    const float* __restrict__ dst_feat,
    const int* __restrict__ counts,
    const int* __restrict__ ent,
    float* __restrict__ out)
{
    __shared__ int bucket_w[RANGE * BSTRIDE];   // 6656 B
    __shared__ int cnt_s[256];                  // 250 real + 6 zero pads
    __shared__ int c[RANGE];

    int r = blockIdx.x;
    if (r >= NBINS) r -= NBINS;                 // diagnostic duplicate half
    int tid = threadIdx.x;
    int wave = tid >> 6;
    int lane = tid & 63;

    // Unconditional ent prefetch: 8 coalesced ints per thread, issued FIRST.
    const int* er = ent + (size_t)r * RSTRIDE;
    int ew[8];
    #pragma unroll
    for (int k = 0; k < 8; ++k)
        ew[k] = er[tid + k * 512];

    // Scattered counts reads ([b][r] layout), one per bin-block.
    if (tid < 256) cnt_s[tid] = (tid < K1B) ? counts[tid * NBINS + r] : 0;
    if (tid < RANGE) c[tid] = 0;

    // dst rows: consumed only in the epilogue (latency free).
    float Bv[4];
    #pragma unroll
    for (int m = 0; m < 4; ++m) {
        int n = r * RANGE + wave * 4 + m;
        Bv[m] = (n < N_NODES) ? dst_feat[n * FEAT + lane] : 0.f;
    }
    __syncthreads();

    // Phase A: filter prefetched slots, sort into per-node u32 buckets.
    #pragma unroll
    for (int k = 0; k < 8; ++k) {
        int g = tid + k * 512;
        int bb = g >> 4;              // SUB == 16
        int s  = g & 15;
        if (s < cnt_s[bb]) {
            int p = ew[k];
            int dl = p >> 16;
            int pos = atomicAdd(&c[dl], 1);
            if (pos < CAPP) bucket_w[dl * BSTRIDE + pos] = p & 0xFFFF;
        }
    }
    __syncthreads();

    // Pad each node's count to a multiple of 4 with the zero dummy row.
    if (tid < RANGE) {
        int cc = c[tid]; if (cc > CAPP) cc = CAPP;
        while (cc & 3) bucket_w[tid * BSTRIDE + cc++] = DUMMY;
        c[tid] = cc >> 2;             // rows-of-4 count
    }
    __syncthreads();

    // Phase B: wide gather, 2-deep pipelined.
    int sub = lane >> 4;
    int fc  = lane & 15;
    int rows4[4], qmax = 0;
    #pragma unroll
    for (int m = 0; m < 4; ++m) {
        rows4[m] = c[wave * 4 + m];
        qmax = (rows4[m] > qmax) ? rows4[m] : qmax;
    }

    float acc[4][4] = {{0.f,0.f,0.f,0.f},{0.f,0.f,0.f,0.f},
                       {0.f,0.f,0.f,0.f},{0.f,0.f,0.f,0.f}};
    {
        int idA[4], idB[4];
        uint2 LA[4], LB[4];
        if (qmax > 0) { RDIDX(idA, 0); GLOAD(LA, idA); }
        int q = 0;
        while (q < qmax) {           // qmax wave-uniform -> no divergence
            int qn = q + 1;
            if (qn < qmax) { RDIDX(idB, qn); GLOAD(LB, idB); }
            ACCUM(LA);
            q = qn;
            if (q >= qmax) break;
            qn = q + 1;
            if (qn < qmax) { RDIDX(idA, qn); GLOAD(LA, idA); }
            ACCUM(LB);
            q = qn;
        }
    }

    // Butterfly-reduce the 4 row-slots.
    #pragma unroll
    for (int m = 0; m < 4; ++m) {
        #pragma unroll
        for (int u = 0; u < 4; ++u) {
            acc[m][u] += __shfl_xor(acc[m][u], 16, 64);
            acc[m][u] += __shfl_xor(acc[m][u], 32, 64);
        }
    }

    // Epilogue: 8x8 matmul. S feature 8i+p lives in lane 2i+(p>>2), reg p&3.
    int i = lane >> 3;
    int j = lane & 7;
    #pragma unroll
    for (int m = 0; m < 4; ++m) {
        int n = r * RANGE + wave * 4 + m;
        if (n >= N_NODES) break;
        float res = 0.0f;
        #pragma unroll
        for (int p = 0; p < 8; ++p) {
            float s_ip = __shfl(acc[m][p & 3], 2 * i + (p >> 2), 64);
            float b_pj = __shfl(Bv[m], p * 8 + j, 64);
            res += s_ip * b_pj;
        }
        out[n * FEAT + lane] = res * 0.35355339059327373f;  // 1/sqrt(8)
    }
}

extern "C" void kernel_launch(void* const* d_in, const int* in_sizes, int n_in,
                              void* d_out, int out_size, void* d_ws, size_t ws_size,
                              hipStream_t stream) {
    const float* src_feat = (const float*)d_in[0];
    const float* dst_feat = (const float*)d_in[1];
    const int* edge_src = (const int*)d_in[2];
    const int* edge_dst = (const int*)d_in[3];
    float* out = (float*)d_out;

    // ws layout: counts [K1B][NBINS] 1,563,000 B (pad to 1,563,008)
    //            ent    [NBINS][RSTRIDE] ints = 25,608,192 B
    //            src16  (N_NODES+1)*FEAT u16  =  6,400,128 B   (~33.6 MB)
    char* w = (char*)d_ws;
    int* counts = (int*)w;                        w += 1563008;
    int* ent = (int*)w;                           w += (size_t)NBINS * RSTRIDE * 4;
    unsigned short* src16 = (unsigned short*)w;

    // DIAGNOSTIC: double-launch K01 (idempotent; Ddur += K01).
    conv_bin_kernel<<<CONVB + K1B, 1024, 0, stream>>>(
        src_feat, src16, edge_src, edge_dst, counts, ent);
    conv_bin_kernel<<<CONVB + K1B, 1024, 0, stream>>>(
        src_feat, src16, edge_src, edge_dst, counts, ent);

    // DIAGNOSTIC: 2x grid K2 (benign WAW; one dispatch of ~2xK2 duration).
    sort_gather_mm_kernel<<<2 * NBINS, 512, 0, stream>>>(
        src16, dst_feat, counts, ent, out);
}

// Round 3
// 118.526 us; speedup vs baseline: 1.2715x; 1.2715x over previous
//
#include <hip/hip_runtime.h>
#include <hip/hip_bf16.h>

#define N_NODES 50000
#define N_EDGES 800000
#define FEAT 64
#define RANGE 32        // nodes per K2 block
#define NBINS 1563      // ceil(50000/32)
#define K1B 250         // bin blocks; EPB = 3200 (multiple of 4)
#define EPB (N_EDGES / K1B)
#define SUB 16          // slots per (range, bin-block) chunk; fill ~ Poisson(2.05)
#define RSTRIDE 4096    // ent ints per range: 256 padded chunks x 16 (guard-free prefetch)
#define CAPP 48         // per-node bucket capacity (deg ~ Poisson(16); P(>48) ~ 1e-11)
#define BSTRIDE 52      // bucket row stride in ints (16B-aligned, odd bank step)
#define DUMMY N_NODES   // zero row index for degree padding
#define CONVB 391       // ceil((N_NODES+1)*FEAT/8 / 1024) conv blocks in fused K01

// ============================================================================
// SESSION LEDGER
//  R2 diagnostic: K01 ~6.3us, K2 ~28.8us (57.5us at 2x grid, hbm 30%, VALU 37%,
//     occ 69%), fixed floor (poison fill + restore train + gaps) ~80us.
//  R3 theory: K2 overfetches metadata — counts[b][r] b-major scatter costs
//     ~25MB HBM (64B line per 4B cursor) + 250 scattered-line latencies/block.
//     Fix: counts as uint8 (line shared by 64 r-blocks via L2/L3) + ent
//     prefetch as 2x dwordx4 (chunk-uniform quads). Predict K2 -> ~22us,
//     dur 115.7 -> ~108.
// ============================================================================

static __device__ __forceinline__ unsigned short f2bu(float f) {
    __hip_bfloat16 h = __float2bfloat16(f);
    return __builtin_bit_cast(unsigned short, h);
}

// K01: fused conv + bin (16 waves/CU bin part; conv overlaps bin).
__global__ __launch_bounds__(1024) void conv_bin_kernel(
    const float* __restrict__ src_feat,
    unsigned short* __restrict__ src16,
    const int* __restrict__ edge_src,
    const int* __restrict__ edge_dst,
    unsigned char* __restrict__ counts8,  // [K1B][NBINS] u8 (b-major publish)
    int* __restrict__ ent)                // [NBINS][RSTRIDE]; chunk (r,b) at r*4096+b*16
{
    __shared__ int h[NBINS];        // 6.25 KB cursors (bin blocks only)
    int tid = threadIdx.x;

    if (blockIdx.x < CONVB) {
        // ---- conv part: 8 floats -> 8 bf16 per thread ----
        int base = (blockIdx.x * 1024 + tid) * 8;
        if (base >= (N_NODES + 1) * FEAT) return;
        uint4 o;
        if (base < N_NODES * FEAT) {
            float4 a = *(const float4*)(src_feat + base);
            float4 b = *(const float4*)(src_feat + base + 4);
            o.x = (unsigned)f2bu(a.x) | ((unsigned)f2bu(a.y) << 16);
            o.y = (unsigned)f2bu(a.z) | ((unsigned)f2bu(a.w) << 16);
            o.z = (unsigned)f2bu(b.x) | ((unsigned)f2bu(b.y) << 16);
            o.w = (unsigned)f2bu(b.z) | ((unsigned)f2bu(b.w) << 16);
        } else {
            o = make_uint4(0, 0, 0, 0);
        }
        *(uint4*)(src16 + base) = o;
        return;
    }

    // ---- bin part: deterministic single-pass binning ----
    int b = blockIdx.x - CONVB;
    for (int r = tid; r < NBINS; r += 1024) h[r] = 0;
    __syncthreads();

    if (tid < EPB / 4) {            // exactly 800 threads, one int4 each
        int e = b * EPB + tid * 4;
        int4 s4 = *(const int4*)(edge_src + e);
        int4 d4 = *(const int4*)(edge_dst + e);
        int r0 = d4.x >> 5, r1 = d4.y >> 5, r2 = d4.z >> 5, r3 = d4.w >> 5;
        int p0 = atomicAdd(&h[r0], 1);
        int p1 = atomicAdd(&h[r1], 1);
        int p2 = atomicAdd(&h[r2], 1);
        int p3 = atomicAdd(&h[r3], 1);
        if (p0 < SUB) ent[r0 * RSTRIDE + b * SUB + p0] = ((d4.x & 31) << 16) | s4.x;
        if (p1 < SUB) ent[r1 * RSTRIDE + b * SUB + p1] = ((d4.y & 31) << 16) | s4.y;
        if (p2 < SUB) ent[r2 * RSTRIDE + b * SUB + p2] = ((d4.z & 31) << 16) | s4.z;
        if (p3 < SUB) ent[r3 * RSTRIDE + b * SUB + p3] = ((d4.w & 31) << 16) | s4.w;
    }
    __syncthreads();

    // Publish counts as BYTES: 1563 B contiguous per block.
    for (int r = tid; r < NBINS; r += 1024) {
        int c = h[r];
        counts8[(size_t)b * NBINS + r] = (unsigned char)((c > SUB) ? SUB : c);
    }
}

// Phase-B pipeline macros — all array indices compile-time (rule #20).
#define RDIDX(ID, Q)                                                          \
    _Pragma("unroll")                                                         \
    for (int m_ = 0; m_ < 4; ++m_) {                                          \
        int raw_ = bucket_w[(wave * 4 + m_) * BSTRIDE + (Q) * 4 + sub];       \
        ID[m_] = ((Q) < rows4[m_]) ? raw_ : DUMMY;                            \
    }
#define GLOAD(L, ID)                                                          \
    _Pragma("unroll")                                                         \
    for (int m_ = 0; m_ < 4; ++m_)                                            \
        L[m_] = *(const uint2*)(src16 + (size_t)ID[m_] * FEAT + fc * 4);
#define ACCUM(L)                                                              \
    _Pragma("unroll")                                                         \
    for (int m_ = 0; m_ < 4; ++m_) {                                          \
        acc[m_][0] += __uint_as_float(L[m_].x << 16);                         \
        acc[m_][1] += __uint_as_float(L[m_].x & 0xFFFF0000u);                 \
        acc[m_][2] += __uint_as_float(L[m_].y << 16);                         \
        acc[m_][3] += __uint_as_float(L[m_].y & 0xFFFF0000u);                 \
    }

// K2: guard-free ent prefetch (now 2x dwordx4/thread) -> LDS fine-sort ->
// 2-deep pipelined 4-rows-per-load gather -> butterfly reduce -> fused 8x8x8.
__global__ __launch_bounds__(512, 6) void sort_gather_mm_kernel(
    const unsigned short* __restrict__ src16,
    const float* __restrict__ dst_feat,
    const unsigned char* __restrict__ counts8,
    const int* __restrict__ ent,
    float* __restrict__ out)
{
    __shared__ int bucket_w[RANGE * BSTRIDE];   // 6656 B
    __shared__ int cnt_s[256];                  // 250 real + 6 zero pads
    __shared__ int c[RANGE];

    int r = blockIdx.x;
    int tid = threadIdx.x;
    int wave = tid >> 6;
    int lane = tid & 63;

    // Unconditional ent prefetch: 2 dwordx4 per thread (4096 slots total).
    // 2048 % 16 == 0 and tid*4 % 16 in {0,4,8,12} -> each int4 lies in ONE
    // chunk, so phase A can look the count up once per quad.
    const int* er = ent + (size_t)r * RSTRIDE;
    int4 ew[2];
    #pragma unroll
    for (int k = 0; k < 2; ++k)
        ew[k] = *(const int4*)(er + tid * 4 + k * 2048);

    // counts: 250 scattered BYTE reads ([b][r] layout); unique data 390KB so
    // lines are L2/L3-shared across 64 consecutive r-blocks.
    if (tid < 256) cnt_s[tid] = (tid < K1B) ? (int)counts8[(size_t)tid * NBINS + r] : 0;
    if (tid < RANGE) c[tid] = 0;

    // dst rows: consumed only in the epilogue (latency free).
    float Bv[4];
    #pragma unroll
    for (int m = 0; m < 4; ++m) {
        int n = r * RANGE + wave * 4 + m;
        Bv[m] = (n < N_NODES) ? dst_feat[n * FEAT + lane] : 0.f;
    }
    __syncthreads();

    // Phase A: filter prefetched slots, sort into per-node u32 buckets.
    #pragma unroll
    for (int k = 0; k < 2; ++k) {
        int base = tid * 4 + k * 2048;
        int bb = base >> 4;           // chunk index (uniform over the quad)
        int s0 = base & 15;           // 0,4,8,12
        int cnt = cnt_s[bb];
        int vals[4] = {ew[k].x, ew[k].y, ew[k].z, ew[k].w};
        #pragma unroll
        for (int j = 0; j < 4; ++j) {
            if (s0 + j < cnt) {
                int p = vals[j];
                int dl = p >> 16;
                int pos = atomicAdd(&c[dl], 1);
                if (pos < CAPP) bucket_w[dl * BSTRIDE + pos] = p & 0xFFFF;
            }
        }
    }
    __syncthreads();

    // Pad each node's count to a multiple of 4 with the zero dummy row.
    if (tid < RANGE) {
        int cc = c[tid]; if (cc > CAPP) cc = CAPP;
        while (cc & 3) bucket_w[tid * BSTRIDE + cc++] = DUMMY;
        c[tid] = cc >> 2;             // rows-of-4 count
    }
    __syncthreads();

    // Phase B: wide gather, 2-deep pipelined. Lane covers row-slot (lane>>4),
    // features (lane&15)*4. One dwordx2 load = 4 rows x 128B per wave-instr.
    int sub = lane >> 4;
    int fc  = lane & 15;
    int rows4[4], qmax = 0;
    #pragma unroll
    for (int m = 0; m < 4; ++m) {
        rows4[m] = c[wave * 4 + m];
        qmax = (rows4[m] > qmax) ? rows4[m] : qmax;
    }

    float acc[4][4] = {{0.f,0.f,0.f,0.f},{0.f,0.f,0.f,0.f},
                       {0.f,0.f,0.f,0.f},{0.f,0.f,0.f,0.f}};
    {
        int idA[4], idB[4];
        uint2 LA[4], LB[4];
        if (qmax > 0) { RDIDX(idA, 0); GLOAD(LA, idA); }
        int q = 0;
        while (q < qmax) {           // qmax wave-uniform -> no divergence
            int qn = q + 1;
            if (qn < qmax) { RDIDX(idB, qn); GLOAD(LB, idB); }
            ACCUM(LA);
            q = qn;
            if (q >= qmax) break;
            qn = q + 1;
            if (qn < qmax) { RDIDX(idA, qn); GLOAD(LA, idA); }
            ACCUM(LB);
            q = qn;
        }
    }

    // Butterfly-reduce the 4 row-slots.
    #pragma unroll
    for (int m = 0; m < 4; ++m) {
        #pragma unroll
        for (int u = 0; u < 4; ++u) {
            acc[m][u] += __shfl_xor(acc[m][u], 16, 64);
            acc[m][u] += __shfl_xor(acc[m][u], 32, 64);
        }
    }

    // Epilogue: 8x8 matmul. S feature 8i+p lives in lane 2i+(p>>2), reg p&3.
    int i = lane >> 3;
    int j = lane & 7;
    #pragma unroll
    for (int m = 0; m < 4; ++m) {
        int n = r * RANGE + wave * 4 + m;
        if (n >= N_NODES) break;
        float res = 0.0f;
        #pragma unroll
        for (int p = 0; p < 8; ++p) {
            float s_ip = __shfl(acc[m][p & 3], 2 * i + (p >> 2), 64);
            float b_pj = __shfl(Bv[m], p * 8 + j, 64);
            res += s_ip * b_pj;
        }
        out[n * FEAT + lane] = res * 0.35355339059327373f;  // 1/sqrt(8)
    }
}

extern "C" void kernel_launch(void* const* d_in, const int* in_sizes, int n_in,
                              void* d_out, int out_size, void* d_ws, size_t ws_size,
                              hipStream_t stream) {
    const float* src_feat = (const float*)d_in[0];
    const float* dst_feat = (const float*)d_in[1];
    const int* edge_src = (const int*)d_in[2];
    const int* edge_dst = (const int*)d_in[3];
    float* out = (float*)d_out;

    // ws layout: counts8 [K1B][NBINS] u8 = 390,750 B (pad to 390,752)
    //            ent     [NBINS][RSTRIDE] ints = 25,608,192 B
    //            src16   (N_NODES+1)*FEAT u16  =  6,400,128 B   (~32.4 MB)
    char* w = (char*)d_ws;
    unsigned char* counts8 = (unsigned char*)w;   w += 390752;
    int* ent = (int*)w;                           w += (size_t)NBINS * RSTRIDE * 4;
    unsigned short* src16 = (unsigned short*)w;

    conv_bin_kernel<<<CONVB + K1B, 1024, 0, stream>>>(
        src_feat, src16, edge_src, edge_dst, counts8, ent);

    sort_gather_mm_kernel<<<NBINS, 512, 0, stream>>>(
        src16, dst_feat, counts8, ent, out);
}